// Round 11
// baseline (224.957 us; speedup 1.0000x reference)
//
#include <hip/hip_runtime.h>
#include <stdint.h>

typedef uint16_t u16;
typedef uint32_t u32;
typedef __attribute__((ext_vector_type(4))) float f32x4;
typedef __attribute__((ext_vector_type(4))) unsigned short us4;

#define NB   16
#define NN   512
#define FF   625      // H*W
#define FH   937      // int(625*1.5)
#define ROWS 8192     // NB*NN
#define KS1  1280     // [X(625) pad->640 | t1(625) pad->640]
#define KS2  1920     // [h(937) pad->960 | t2(937) pad->960]
#define NPX  640      // padded F
#define NPH  960      // padded Fh
#define F4   160      // 640/4 f32x4 slots per padded X row
#define ITILE 4       // i-rows per build_L block

using frag_ab = __attribute__((ext_vector_type(8))) short;  // 8 bf16
using frag_cd = __attribute__((ext_vector_type(4))) float;  // 4 fp32

__device__ __forceinline__ u16 f32_bf16(float f) {
  union { float f; uint32_t u; } x; x.f = f;
  uint32_t r = x.u + 0x7fffu + ((x.u >> 16) & 1u);   // RNE
  return (u16)(r >> 16);
}
__device__ __forceinline__ void gload_lds16(const void* g, void* l) {
  __builtin_amdgcn_global_load_lds((__attribute__((address_space(1))) void*)g,
                                   (__attribute__((address_space(3))) void*)l,
                                   16, 0, 0);
}
// VALU cross-lane add via DPP row rotate (no DS-pipe traffic).
// row_ror:8 == xor8 exactly; ror:4/2/1 == xor4/2/1 given wider steps done
// (lane groups bitwise-equal) -> reduction tree bitwise-identical to
// shfl_xor 32,16,8,4,2,1 descending.
template <int CTRL>
__device__ __forceinline__ float dpp_addf(float x) {
  union { float f; int i; } a, b;
  a.f = x;
  b.i = __builtin_amdgcn_update_dpp(0, a.i, CTRL, 0xF, 0xF, true);
  return x + b.f;
}

// ---------------------------------------------------------------------------
// prep (unchanged from R10): fused Xt+pad_x (x4 read once), W1t, W2t,
// att sort + gmask zeroing.
// ---------------------------------------------------------------------------
__global__ __launch_bounds__(256) void prep(
    const float* __restrict__ x4, const float* __restrict__ att,
    const float* __restrict__ W1, const float* __restrict__ W2,
    f32x4* __restrict__ Xpad, u16* __restrict__ Xcat, u16* __restrict__ Xt,
    u16* __restrict__ W1t, u16* __restrict__ W2t,
    float* __restrict__ att_s, u16* __restrict__ ord_g, u32* __restrict__ gmask)
{
  const int blk = blockIdx.x;
  const int tid = threadIdx.x;
  if (blk < 5120) {
    __shared__ float tile[32][33];
    const int xcd = blk & 7, sub = blk >> 3;      // sub 0..639
    const int b = xcd * 2 + sub / 320;            // XCD-aligned batch
    const int t = sub % 320;
    const int ft = t % 20, kt = t / 20;
    const int tx = tid & 31, ty = tid >> 5;
    #pragma unroll
    for (int r = 0; r < 4; ++r) {
      const int node = kt * 32 + ty + r * 8;
      const int f = ft * 32 + tx;
      tile[ty + r * 8][tx] = (f < FF) ? x4[((size_t)b * NN + node) * FF + f] : 0.f;
    }
    __syncthreads();
    #pragma unroll
    for (int r = 0; r < 4; ++r) {                 // Xt (transposed) write
      const int f = ft * 32 + ty + r * 8;
      const int node = kt * 32 + tx;
      Xt[((size_t)b * NPX + f) * 512 + node] = f32_bf16(tile[tx][ty + r * 8]);
    }
    const int nd = tid >> 3, sl = tid & 7;        // pad_x from same tile
    const int row = b * NN + kt * 32 + nd;
    f32x4 v; us4 o;
    #pragma unroll
    for (int t2 = 0; t2 < 4; ++t2) {
      const float x = tile[nd][sl * 4 + t2];
      v[t2] = x; o[t2] = f32_bf16(x);
    }
    Xpad[(size_t)row * F4 + ft * 8 + sl] = v;
    *(us4*)(Xcat + (size_t)row * KS1 + ft * 32 + sl * 4) = o;
  } else if (blk < 6400) {
    __shared__ float tile[32][33];
    const int bb = blk - 5120;                    // 40 kt x 32 nt
    const int kt = bb % 40, nt = bb / 40;
    const int tx = tid & 31, ty = tid >> 5;
    #pragma unroll
    for (int r = 0; r < 4; ++r) {
      int k = kt * 32 + ty + r * 8;
      int n = nt * 32 + tx;
      float v = 0.f;
      int c = -1, kk = 0;
      if (k < 625) { c = 0; kk = k; }
      else if (k >= 640 && k < 1265) { c = 1; kk = k - 640; }
      if (c >= 0 && n < FH) v = W1[((size_t)c * 625 + kk) * FH + n];
      tile[ty + r * 8][tx] = v;
    }
    __syncthreads();
    #pragma unroll
    for (int r = 0; r < 4; ++r) {
      int n = nt * 32 + ty + r * 8;
      int k = kt * 32 + tx;
      W1t[(size_t)n * KS1 + k] = f32_bf16(tile[tx][ty + r * 8]);
    }
  } else if (blk < 7600) {
    __shared__ float tile[32][33];
    const int bb = blk - 6400;                    // 60 kt x 20 nt
    const int kt = bb % 60, nt = bb / 60;
    const int tx = tid & 31, ty = tid >> 5;
    #pragma unroll
    for (int r = 0; r < 4; ++r) {
      int k = kt * 32 + ty + r * 8;
      int n = nt * 32 + tx;
      float v = 0.f;
      int c = -1, kk = 0;
      if (k < 937) { c = 0; kk = k; }
      else if (k >= 960 && k < 1897) { c = 1; kk = k - 960; }
      if (c >= 0 && n < FF) v = W2[((size_t)c * 937 + kk) * FF + n];
      tile[ty + r * 8][tx] = v;
    }
    __syncthreads();
    #pragma unroll
    for (int r = 0; r < 4; ++r) {
      int n = nt * 32 + ty + r * 8;
      int k = kt * 32 + tx;
      W2t[(size_t)n * KS2 + k] = f32_bf16(tile[tx][ty + r * 8]);
    }
  } else {
    __shared__ float sa[512];
    __shared__ u16 so[512];
    const int b = blk - 7600;
    u32* gm = gmask + (size_t)b * 512 * 16;       // zero this batch's gmask
    for (int s = tid; s < 512 * 16; s += 256) gm[s] = 0;
    sa[tid] = att[b * NN + tid]; sa[tid + 256] = att[b * NN + tid + 256];
    so[tid] = (u16)tid; so[tid + 256] = (u16)(tid + 256);
    for (int k = 2; k <= 512; k <<= 1) {
      for (int j = k >> 1; j > 0; j >>= 1) {
        __syncthreads();
        const int i = ((tid & ~(j - 1)) << 1) | (tid & (j - 1));
        const int p = i | j;
        const bool up = ((i & k) == 0);
        const float va = sa[i], vp = sa[p];
        if ((va > vp) == up) {
          sa[i] = vp; sa[p] = va;
          const u16 t = so[i]; so[i] = so[p]; so[p] = t;
        }
      }
    }
    __syncthreads();
    att_s[b * NN + tid] = sa[tid]; att_s[b * NN + tid + 256] = sa[tid + 256];
    ord_g[b * NN + tid] = so[tid]; ord_g[b * NN + tid + 256] = so[tid + 256];
  }
}

// ---------------------------------------------------------------------------
// build_L4: R10 structure (symmetric upper-triangle, wave-uniform j, gmask)
// with the DS pipe starved: Xi hoisted to REGISTERS once per wave (was 12
// ds_read_b128 per j-iter), butterfly = shfl_xor {32,16} + DPP row_ror
// {8,4,2,1} VALU adds (was 24 DS shfls). Reduction tree bitwise-identical.
// ---------------------------------------------------------------------------
__global__ __launch_bounds__(256) void build_L4(
    const f32x4* __restrict__ Xpad,
    const float* __restrict__ att_s, const u16* __restrict__ ord_g,
    u32* __restrict__ gmask)
{
  __shared__ f32x4 Xi[ITILE][F4];   // 10 KB (read once per wave into regs)
  __shared__ float as_[512];
  __shared__ u16 ord[512];
  __shared__ int jhi_s;

  const int tid = threadIdx.x;
  const int blk = blockIdx.x;                  // 2048, XCD = blk&7
  const int xcd = blk & 7, sub = blk >> 3;
  const int b = xcd * 2 + (sub >> 7);
  const int s0 = (sub & 127) * ITILE;
  const f32x4* Xb4 = Xpad + (size_t)b * NN * F4;

  as_[tid] = att_s[b * NN + tid]; as_[tid + 256] = att_s[b * NN + tid + 256];
  ord[tid] = ord_g[b * NN + tid]; ord[tid + 256] = ord_g[b * NN + tid + 256];
  __syncthreads();

  for (int s = tid; s < ITILE * F4; s += 256) {
    const int ii = s / F4, k4 = s - ii * F4;
    Xi[ii][k4] = Xb4[(size_t)ord[s0 + ii] * F4 + k4];
  }
  if (tid == 0) {
    const float hit = as_[s0 + ITILE - 1] + 0.05f;
    int lo = 0, hi = 512;
    while (lo < hi) { int m = (lo + hi) >> 1; if (as_[m] <= hit) lo = m + 1; else hi = m; }
    jhi_s = lo;
  }
  __syncthreads();

  const int lane = tid & 63;
  const int wave = tid >> 6;
  const int jhi = jhi_s;
  const f32x4 zero = {0.f, 0.f, 0.f, 0.f};

  // Xi -> registers (loop-invariant; one-time LDS read)
  f32x4 a0[ITILE], a1[ITILE], a2[ITILE];
  #pragma unroll
  for (int ii = 0; ii < ITILE; ++ii) {
    a0[ii] = Xi[ii][lane];
    a1[ii] = Xi[ii][64 + lane];
    a2[ii] = (lane < 32) ? Xi[ii][128 + lane] : zero;
  }

  for (int sj = s0 + 1 + wave; sj < jhi; sj += 4) {
    const int oj = __builtin_amdgcn_readfirstlane((int)ord[sj]);
    const f32x4* Xj = Xb4 + (size_t)oj * F4;     // SGPR base + lane offset
    const f32x4 xj0 = Xj[lane];
    const f32x4 xj1 = Xj[64 + lane];
    const f32x4 xj2 = (lane < 32) ? Xj[128 + lane] : zero;
    const float aj = as_[sj];
    f32x4 pv;
    #pragma unroll
    for (int ii = 0; ii < ITILE; ++ii) {
      const f32x4 d0 = a0[ii] - xj0;
      const f32x4 d1 = a1[ii] - xj1;
      const f32x4 d2 = a2[ii] - xj2;
      float p = 0.f;
      #pragma unroll
      for (int t = 0; t < 4; ++t)
        p += fabsf(d0[t]) + fabsf(d1[t]) + fabsf(d2[t]);
      pv[ii] = p;
    }
    // descending butterfly 32,16 (DS) then 8,4,2,1 (DPP, zero DS ops)
    #pragma unroll
    for (int t = 0; t < 4; ++t) pv[t] += __shfl_xor(pv[t], 32, 64);
    #pragma unroll
    for (int t = 0; t < 4; ++t) pv[t] += __shfl_xor(pv[t], 16, 64);
    #pragma unroll
    for (int t = 0; t < 4; ++t) pv[t] = dpp_addf<0x128>(pv[t]);  // ror:8 = xor8
    #pragma unroll
    for (int t = 0; t < 4; ++t) pv[t] = dpp_addf<0x124>(pv[t]);  // = xor4
    #pragma unroll
    for (int t = 0; t < 4; ++t) pv[t] = dpp_addf<0x122>(pv[t]);  // = xor2
    #pragma unroll
    for (int t = 0; t < 4; ++t) pv[t] = dpp_addf<0x121>(pv[t]);  // = xor1
    if (lane == 0) {
      #pragma unroll
      for (int ii = 0; ii < ITILE; ++ii) {
        const int si = s0 + ii;
        if (sj > si && fabsf(aj - as_[si]) <= 0.05f && pv[ii] <= 180.0f) {
          atomicOr(&gmask[((size_t)b * 512 + si) * 16 + (sj >> 5)], 1u << (sj & 31));
          atomicOr(&gmask[((size_t)b * 512 + sj) * 16 + (si >> 5)], 1u << (si & 31));
        }
      }
    }
  }
}

// ---------------------------------------------------------------------------
// write_L (unchanged): gmask -> full coalesced L rows in original coords.
// ---------------------------------------------------------------------------
__global__ __launch_bounds__(256) void write_L(
    const u32* __restrict__ gmask, const u16* __restrict__ ord_g,
    u16* __restrict__ L)
{
  __shared__ u32 msk[16][16];
  __shared__ u16 ord[512];
  __shared__ u16 inv[512];
  __shared__ u16 dvs[16];

  const int tid = threadIdx.x;
  const int blk = blockIdx.x;                  // 512
  const int xcd = blk & 7, sub = blk >> 3;
  const int b = xcd * 2 + (sub >> 5);
  const int s0 = (sub & 31) * 16;

  const u16 o0 = ord_g[b * NN + tid], o1 = ord_g[b * NN + tid + 256];
  ord[tid] = o0; ord[tid + 256] = o1;
  inv[o0] = (u16)tid; inv[o1] = (u16)(tid + 256);
  if (tid < 256) msk[tid >> 4][tid & 15] =
      gmask[((size_t)b * 512 + s0 + (tid >> 4)) * 16 + (tid & 15)];
  __syncthreads();

  if (tid < 16) {
    int d = 0;
    #pragma unroll
    for (int w = 0; w < 16; ++w) d += __popc(msk[tid][w]);
    dvs[tid] = f32_bf16(1.0f / (float)(d + 1));
  }
  __syncthreads();

  #pragma unroll 4
  for (int ii = 0; ii < 16; ++ii) {
    const int oi = ord[s0 + ii];
    const u16 dv = dvs[ii];
    const int j0 = 2 * tid;
    const int sA = inv[j0], sB = inv[j0 + 1];
    const u32 fA = (j0 == oi)     | ((msk[ii][sA >> 5] >> (sA & 31)) & 1u);
    const u32 fB = (j0 + 1 == oi) | ((msk[ii][sB >> 5] >> (sB & 31)) & 1u);
    *(u32*)(L + ((size_t)b * 512 + oi) * 512 + j0) =
        (fA ? (u32)dv : 0u) | ((fB ? (u32)dv : 0u) << 16);
  }
}

// ---------------------------------------------------------------------------
// gemm_core: MTILE x NTILE tile, BK=64, XOR chunk swizzle. MTILE=64 variants
// double/triple blocks/CU vs 128 (R10 GEMMs sat at 2/CU; m114: co-resident
// blocks hide each other's barrier drains).
// ---------------------------------------------------------------------------
template <int KS, int MTILE, int NTILE, int NREAL, int NSTORE,
          bool RELU, bool BIAS, bool OUT_BF16>
__device__ __forceinline__ void gemm_core(
    const u16* __restrict__ At, const u16* __restrict__ Btt,
    const float* __restrict__ bias, void* __restrict__ C,
    long crow0, int col0, int ldc)
{
  constexpr int MI = MTILE / 32;
  constexpr int NI = NTILE / 32;
  constexpr int AR = MTILE / 32;        // A staging rounds
  constexpr int BR = NTILE / 32;        // B staging rounds
  __shared__ __align__(16) u16 Ash[MTILE * 64];
  __shared__ __align__(16) u16 Bsh[NTILE * 64];

  const int tid  = threadIdx.x;
  const int lane = tid & 63;
  const int wave = tid >> 6;
  const int wm = wave & 1, wn = wave >> 1;
  const int q = lane >> 4, l16 = lane & 15;

  const u16* pa[AR]; const u16* pb[BR];
  #pragma unroll
  for (int r = 0; r < AR; ++r) {
    const int ci = r * 256 + tid;
    const int row = ci >> 3, cpos = ci & 7;
    pa[r] = At + (size_t)row * KS + (cpos ^ (row & 7)) * 8;
  }
  #pragma unroll
  for (int r = 0; r < BR; ++r) {
    const int ci = r * 256 + tid;
    const int row = ci >> 3, cpos = ci & 7;
    pb[r] = Btt + (size_t)row * KS + (cpos ^ (row & 7)) * 8;
  }
  const int wbase = (tid & 192) * 8;

  const frag_ab* fA[MI][2]; const frag_ab* fB[NI][2];
  #pragma unroll
  for (int mi = 0; mi < MI; ++mi) {
    const int row = wm * (MTILE / 2) + mi * 16 + l16;
    fA[mi][0] = (const frag_ab*)&Ash[row * 64 + ((q    ) ^ (l16 & 7)) * 8];
    fA[mi][1] = (const frag_ab*)&Ash[row * 64 + ((q + 4) ^ (l16 & 7)) * 8];
  }
  #pragma unroll
  for (int ni = 0; ni < NI; ++ni) {
    const int row = wn * (NTILE / 2) + ni * 16 + l16;
    fB[ni][0] = (const frag_ab*)&Bsh[row * 64 + ((q    ) ^ (l16 & 7)) * 8];
    fB[ni][1] = (const frag_ab*)&Bsh[row * 64 + ((q + 4) ^ (l16 & 7)) * 8];
  }

  frag_cd acc[MI][NI] = {};

  constexpr int KT = KS / 64;
  for (int kt = 0; kt < KT; ++kt) {
    __syncthreads();
    #pragma unroll
    for (int r = 0; r < AR; ++r) { gload_lds16(pa[r], &Ash[r * 2048 + wbase]); pa[r] += 64; }
    #pragma unroll
    for (int r = 0; r < BR; ++r) { gload_lds16(pb[r], &Bsh[r * 2048 + wbase]); pb[r] += 64; }
    __syncthreads();

    #pragma unroll
    for (int kk = 0; kk < 2; ++kk) {
      frag_ab av[MI], bv[NI];
      #pragma unroll
      for (int mi = 0; mi < MI; ++mi) av[mi] = *fA[mi][kk];
      #pragma unroll
      for (int ni = 0; ni < NI; ++ni) bv[ni] = *fB[ni][kk];
      #pragma unroll
      for (int mi = 0; mi < MI; ++mi)
        #pragma unroll
        for (int ni = 0; ni < NI; ++ni)
          acc[mi][ni] = __builtin_amdgcn_mfma_f32_16x16x32_bf16(
              av[mi], bv[ni], acc[mi][ni], 0, 0, 0);
    }
  }

  #pragma unroll
  for (int ni = 0; ni < NI; ++ni) {
    const int col = col0 + wn * (NTILE / 2) + ni * 16 + l16;
    if (col >= NSTORE) continue;
    const bool ok = (col < NREAL);
    float bvv = 0.f;
    if (BIAS) bvv = ok ? bias[col] : 0.f;
    #pragma unroll
    for (int mi = 0; mi < MI; ++mi) {
      #pragma unroll
      for (int r = 0; r < 4; ++r) {
        const long rowg = crow0 + wm * (MTILE / 2) + mi * 16 + q * 4 + r;
        float v = acc[mi][ni][r];
        if (BIAS) v += bvv;
        if (RELU) v = fmaxf(v, 0.f);
        if (!ok) v = 0.f;
        if (OUT_BF16) ((u16*)C)[rowg * (size_t)ldc + col] = f32_bf16(v);
        else          ((float*)C)[rowg * (size_t)ldc + col] = v;
      }
    }
  }
}

template <int KS, int MTILE, int NTILE, int NREAL, int NSTORE,
          bool RELU, bool BIAS, bool OUT_BF16>
__global__ __launch_bounds__(256) void gemm_dense(
    const u16* __restrict__ A, const u16* __restrict__ Bt,
    const float* __restrict__ bias, void* __restrict__ C, int ldc)
{
  constexpr int MTPX = (ROWS / MTILE) / 8;       // m-tiles per XCD
  const int x = blockIdx.x;
  const int mt = (x & 7) * MTPX + (x >> 3);      // XCD-aligned m-tile
  gemm_core<KS, MTILE, NTILE, NREAL, NSTORE, RELU, BIAS, OUT_BF16>(
      A + (size_t)mt * MTILE * KS, Bt + (size_t)blockIdx.y * NTILE * KS,
      bias, C, (long)mt * MTILE, blockIdx.y * NTILE, ldc);
}

// batched spmm: t = L_b · B_b^T; MTILE=64, batch b on XCD b/2 (L2-local).
template <int NP>
__global__ __launch_bounds__(256) void spmm(
    const u16* __restrict__ L, const u16* __restrict__ Bt,
    u16* __restrict__ C, int ldc)
{
  constexpr int TPB = 8 * (NP / 64);
  const int blk = blockIdx.x;
  const int xcd = blk & 7, sub = blk >> 3;
  const int b = xcd * 2 + sub / TPB;
  const int t = sub % TPB;
  const int mt = t & 7, nt = t >> 3;
  gemm_core<512, 64, 64, NP, NP, false, false, true>(
      L + ((size_t)b * 512 + mt * 64) * 512,
      Bt + ((size_t)b * NP + nt * 64) * 512,
      nullptr, C, (long)b * 512 + mt * 64, nt * 64, ldc);
}

// ---------------------------------------------------------------------------
// transpose_h (unchanged): hcat h-half -> ht [b][960][512] bf16.
// ---------------------------------------------------------------------------
__global__ __launch_bounds__(256) void transpose_h(
    const u16* __restrict__ hcat, u16* __restrict__ ht)
{
  __shared__ u16 tile[32][34];
  const int blk = blockIdx.x;                   // 7680
  const int xcd = blk & 7, sub = blk >> 3;
  const int b = xcd * 2 + sub / 480;
  const int t = sub % 480;
  const int kt = t % 16, nt = t / 16;
  const int tid = threadIdx.x;
  const int tx = tid & 31, ty = tid >> 5;
  #pragma unroll
  for (int r = 0; r < 4; ++r) {
    const int node = kt * 32 + ty + r * 8;
    const int n = nt * 32 + tx;
    tile[ty + r * 8][tx] = hcat[((size_t)b * NN + node) * KS2 + n];
  }
  __syncthreads();
  #pragma unroll
  for (int r = 0; r < 4; ++r) {
    const int n = nt * 32 + ty + r * 8;
    const int node = kt * 32 + tx;
    ht[((size_t)b * NPH + n) * 512 + node] = tile[tx][ty + r * 8];
  }
}

// ---------------------------------------------------------------------------
extern "C" void kernel_launch(void* const* d_in, const int* in_sizes, int n_in,
                              void* d_out, int out_size, void* d_ws, size_t ws_size,
                              hipStream_t stream) {
  const float* x4  = (const float*)d_in[0];
  const float* att = (const float*)d_in[1];
  const float* W1  = (const float*)d_in[2];
  const float* b1  = (const float*)d_in[3];
  const float* W2  = (const float*)d_in[4];
  const float* b2  = (const float*)d_in[5];
  float* out = (float*)d_out;

  char* ws = (char*)d_ws;
  f32x4* Xpad = (f32x4*)ws;                                 // 20.97 MB
  u16* ht = (u16*)ws;       ws += (size_t)ROWS * F4 * 16;   // ht aliases Xpad
  u16* Xcat = (u16*)ws;  ws += (size_t)ROWS * KS1 * 2;      // 20.97 MB
  u16* hcat = (u16*)ws;  ws += (size_t)ROWS * KS2 * 2;      // 31.46 MB
  u16* W1t  = (u16*)ws;  ws += (size_t)1024 * KS1 * 2;      //  2.62 MB
  u16* W2t  = (u16*)ws;  ws += (size_t)640 * KS2 * 2;       //  2.46 MB
  u16* Lm   = (u16*)ws;  ws += (size_t)NB * 512 * 512 * 2;  //  8.39 MB
  u16* Xt   = (u16*)ws;  ws += (size_t)NB * NPX * 512 * 2;  // 10.49 MB
  u32* gmask = (u32*)ws; ws += (size_t)ROWS * 16 * 4;       // 512 KB
  float* att_s = (float*)ws; ws += (size_t)NB * NN * 4;     // 32 KB
  u16* ord_g   = (u16*)ws;   ws += (size_t)NB * NN * 2;     // 16 KB

  prep<<<dim3(7616), 256, 0, stream>>>(x4, att, W1, W2, Xpad, Xcat, Xt,
                                       W1t, W2t, att_s, ord_g, gmask);
  build_L4<<<dim3(2048), 256, 0, stream>>>(Xpad, att_s, ord_g, gmask);
  write_L<<<dim3(512), 256, 0, stream>>>(gmask, ord_g, Lm);
  spmm<NPX><<<dim3(1280), 256, 0, stream>>>(Lm, Xt, Xcat + NPX, KS1);
  gemm_dense<KS1, 64, 128, FH, NPH, true, true, true>
      <<<dim3(128, 8), 256, 0, stream>>>(Xcat, W1t, b1, (void*)hcat, KS2);
  transpose_h<<<dim3(7680), 256, 0, stream>>>(hcat, ht);
  spmm<NPH><<<dim3(1920), 256, 0, stream>>>(Lm, ht, hcat + NPH, KS2);
  gemm_dense<KS2, 64, 64, FF, FF, true, true, false>
      <<<dim3(128, 10), 256, 0, stream>>>(hcat, W2t, b2, (void*)out, FF);
}